// Round 3
// baseline (1111.540 us; speedup 1.0000x reference)
//
#include <hip/hip_runtime.h>
#include <math.h>
#include <stdint.h>

// Shapes (fixed by the reference)
// N=10000, E=100000, G=64, NB=16, EMB=16, S=8, COUT=16, LMAX=2
// WNUM = 3*16*8*8 = 3072 ; ef width = 16 + 48 + 144 = 208
// Per-edge compact result: m[48] (l*16+o) + n[3], stored as 52 floats.

__device__ __forceinline__ float silu_f(float x) {
    return x / (1.0f + __expf(-x));
}

// ---------------- kernel 1: transpose fc_w3 (64 x 3072) -> w3T[lo][ab][c] ----------------
__global__ __launch_bounds__(256) void k_transpose_w3(const float* __restrict__ w3,
                                                      float* __restrict__ w3T) {
    int t = blockIdx.x * 256 + threadIdx.x;       // t = lo*4096 + ab*64 + c
    if (t >= 48 * 64 * 64) return;
    int c  = t & 63;
    int ab = (t >> 6) & 63;
    int lo = t >> 12;
    w3T[t] = w3[c * 3072 + lo * 64 + ab];
}

// ---------------- kernel 2: per-node Ai ----------------
__global__ __launch_bounds__(256) void k_node_ai(const int* __restrict__ A,
                                                 const float* __restrict__ embt,
                                                 const float* __restrict__ w1,
                                                 const float* __restrict__ b1,
                                                 const float* __restrict__ w2,
                                                 const float* __restrict__ b2,
                                                 float* __restrict__ Ai, int N) {
    int i = blockIdx.x * 256 + threadIdx.x;
    if (i >= N) return;
    float e[16];
    const float* er = embt + A[i] * 16;
    #pragma unroll
    for (int k = 0; k < 16; ++k) e[k] = er[k];
    float h1[64];
    #pragma unroll
    for (int j = 0; j < 64; ++j) {
        float a = b1[j];
        #pragma unroll
        for (int k = 0; k < 16; ++k) a = fmaf(e[k], w1[k * 64 + j], a);
        h1[j] = silu_f(a);
    }
    #pragma unroll
    for (int o = 0; o < 8; ++o) {
        float a = b2[o];
        #pragma unroll
        for (int j = 0; j < 64; ++j) a = fmaf(h1[j], w2[j * 8 + o], a);
        Ai[i * 8 + o] = a;
    }
}

// ---------------- kernel 3: histogram of edge_dst ----------------
__global__ __launch_bounds__(256) void k_hist(const int* __restrict__ edst,
                                              int* __restrict__ deg, int E) {
    int e = blockIdx.x * 256 + threadIdx.x;
    if (e < E) atomicAdd(&deg[edst[e]], 1);
}

// ---------------- kernel 4: single-block exclusive scan (N=10000) ----------------
__global__ __launch_bounds__(256) void k_scan(const int* __restrict__ deg,
                                              int* __restrict__ offs,
                                              int* __restrict__ cursor, int N) {
    __shared__ int part[256];
    const int t = threadIdx.x;
    const int chunk = (N + 255) / 256;
    const int beg = t * chunk;
    const int end = min(beg + chunk, N);
    int s = 0;
    for (int i = beg; i < end; ++i) s += deg[i];
    part[t] = s;
    __syncthreads();
    for (int off = 1; off < 256; off <<= 1) {
        int v = (t >= off) ? part[t - off] : 0;
        __syncthreads();
        part[t] += v;
        __syncthreads();
    }
    int run = (t == 0) ? 0 : part[t - 1];
    for (int i = beg; i < end; ++i) {
        offs[i] = run;
        cursor[i] = run;
        run += deg[i];
    }
    if (t == 255) offs[N] = part[255];
}

// ---------------- kernel 5: per-edge compute, split-c across waves ----------------
// Block = 256 threads = 4 waves, covering 64 edges (lane = edge slot).
// Wave p owns c-chunk [16p, 16p+16). Per-thread register state: hc[16] + macc.
// No per-thread 64-float arrays anywhere -> no scratch spill possible.
// w3T/fw1/fw2/b3 streams are wave-uniform -> scalar (SGPR) loads.
__global__ __launch_bounds__(256) void k_edge(
    const float* __restrict__ pos, const int* __restrict__ batch,
    const int* __restrict__ esrc, const int* __restrict__ edst,
    const float* __restrict__ eshift, const float* __restrict__ cell,
    const float* __restrict__ fw1, const float* __restrict__ fb1,
    const float* __restrict__ fw2, const float* __restrict__ fb2,
    const float* __restrict__ w3T, const float* __restrict__ b3,
    const float* __restrict__ Ai, float* __restrict__ ef,
    int* __restrict__ cursor, int* __restrict__ eidx, int E) {

    // s_buf: first used as h1[64 edges][65-pad], then (after barrier) as
    // mpart[4 waves][64 edges][17-pad] for the cross-wave partial reduction.
    __shared__ float s_buf[4 * 64 * 17];     // 4352 floats = 17408 B
    __shared__ float s_o[64 * 65];           // o[e][ab], pad 65 -> conflict-free

    const int tid  = threadIdx.x;
    const int lane = tid & 63;                                   // edge slot
    const int p    = __builtin_amdgcn_readfirstlane(tid >> 6);   // wave id = chunk
    const int e0   = blockIdx.x * 64;
    const int e    = e0 + lane;
    const bool valid = (e < E);
    const int ec   = valid ? e : (E - 1);    // clamped index for safe loads

    const int src = esrc[ec];
    const int dst = edst[ec];

    // ---- geometry (redundant across the 4 waves; cheap) ----
    const int g = batch[src];
    const float s0 = eshift[ec * 3 + 0], s1 = eshift[ec * 3 + 1], s2 = eshift[ec * 3 + 2];
    const float* cl = cell + g * 9;
    float vx = pos[dst * 3 + 0] - pos[src * 3 + 0] + s0 * cl[0] + s1 * cl[3] + s2 * cl[6];
    float vy = pos[dst * 3 + 1] - pos[src * 3 + 1] + s0 * cl[1] + s1 * cl[4] + s2 * cl[7];
    float vz = pos[dst * 3 + 2] - pos[src * 3 + 2] + s0 * cl[2] + s1 * cl[5] + s2 * cl[8];
    float r = sqrtf(vx * vx + vy * vy + vz * vz);
    float rinv = 1.0f / fmaxf(r, 1e-9f);
    float nx = vx * rinv, ny = vy * rinv, nz = vz * rinv;

    // ---- radial basis (NB=16) ----
    float embv[16];
    const float step = 4.0f / 17.0f;
    const float sc = 4.0f / 1.12f;
    #pragma unroll
    for (int k = 0; k < 16; ++k) {
        float d = (r - (float)(k + 1) * step) / step;
        embv[k] = __expf(-d * d) * sc;
    }

    // ---- h1 chunk -> LDS: wave p computes h1[j] for j in [16p, 16p+16) ----
    const int j0 = p * 16;
    #pragma unroll
    for (int jj = 0; jj < 16; ++jj) {
        const int j = j0 + jj;
        float a = fb1[j];
        #pragma unroll
        for (int k = 0; k < 16; ++k) a = fmaf(embv[k], fw1[k * 64 + j], a);
        s_buf[lane * 65 + j] = silu_f(a);
    }

    // ---- o chunk -> LDS: wave p computes o[ab] = fs[a]*fd[b] for ab in [16p,16p+16) ----
    {
        const float* As = Ai + (size_t)src * 8;
        const float* Ad = Ai + (size_t)dst * 8;
        float fsa0 = As[2 * p], fsa1 = As[2 * p + 1];
        float4 d0 = *reinterpret_cast<const float4*>(Ad);
        float4 d1 = *reinterpret_cast<const float4*>(Ad + 4);
        float fdv[8] = {d0.x, d0.y, d0.z, d0.w, d1.x, d1.y, d1.z, d1.w};
        const int ob = lane * 65 + j0;
        #pragma unroll
        for (int i = 0; i < 8; ++i)  s_o[ob + i]     = fsa0 * fdv[i];
        #pragma unroll
        for (int i = 0; i < 8; ++i)  s_o[ob + 8 + i] = fsa1 * fdv[i];
    }
    __syncthreads();   // h1 + o fully written

    // ---- hc chunk (registers): h[c] = silu(sum_j h1[j]*fw2[j][c] + fb2[c]), c in [16p,16p+16) ----
    float hc[16];
    #pragma unroll
    for (int i = 0; i < 16; ++i) hc[i] = fb2[j0 + i];
    #pragma unroll 4
    for (int j = 0; j < 64; ++j) {
        const float v = s_buf[lane * 65 + j];
        const float* w2r = fw2 + j * 64 + j0;   // wave-uniform -> scalar
        #pragma unroll
        for (int i = 0; i < 16; ++i) hc[i] = fmaf(v, w2r[i], hc[i]);
    }
    #pragma unroll
    for (int i = 0; i < 16; ++i) hc[i] = silu_f(hc[i]);
    __syncthreads();   // h1 region now free -> becomes mpart

    // ---- main contraction, lo in 3 groups of 16 ----
    // partial m[lo] = sum_ab (0.25*b3[lo,ab] + sum_{c in chunk} hc*w3T[lo,ab,c]) * o[ab]
    float* mpart = s_buf;                 // [p][64][17]
    const int mbase = p * 1088 + lane * 17;
    const int obase = lane * 65;

    for (int grp = 0; grp < 3; ++grp) {
        for (int l = 0; l < 16; ++l) {
            const int lo = grp * 16 + l;
            const float* wb = w3T + lo * 4096 + j0;   // uniform -> scalar stream
            const float* bb = b3 + lo * 64;
            float macc = 0.0f;
            #pragma unroll 2
            for (int ab = 0; ab < 64; ++ab) {
                const float* wr = wb + ab * 64;
                float u0 = hc[0] * wr[0];
                float u1 = hc[1] * wr[1];
                float u2 = hc[2] * wr[2];
                float u3 = hc[3] * wr[3];
                #pragma unroll
                for (int i = 4; i < 16; i += 4) {
                    u0 = fmaf(hc[i + 0], wr[i + 0], u0);
                    u1 = fmaf(hc[i + 1], wr[i + 1], u1);
                    u2 = fmaf(hc[i + 2], wr[i + 2], u2);
                    u3 = fmaf(hc[i + 3], wr[i + 3], u3);
                }
                const float t = fmaf(0.25f, bb[ab], (u0 + u1) + (u2 + u3));
                macc = fmaf(t, s_o[obase + ab], macc);
            }
            mpart[mbase + l] = macc;
        }
        __syncthreads();
        // reduce 4 partials -> ef ; 256 threads cover 64 edges x 16 lo
        {
            const int le = tid & 63;
            const int l0 = (tid >> 6) * 4;
            if (e0 + le < E) {
                float* dstp = ef + (size_t)(e0 + le) * 52 + grp * 16 + l0;
                #pragma unroll
                for (int q = 0; q < 4; ++q) {
                    const int idx = le * 17 + l0 + q;
                    dstp[q] = s_buf[idx] + s_buf[1088 + idx] +
                              s_buf[2176 + idx] + s_buf[3264 + idx];
                }
            }
        }
        __syncthreads();
    }

    // ---- n + CSR scatter (one thread per edge) ----
    if (p == 0 && valid) {
        float* np = ef + (size_t)e * 52;
        np[48] = nx; np[49] = ny; np[50] = nz;
        int pp = atomicAdd(&cursor[dst], 1);
        eidx[pp] = e;
    }
}

// ---------------- kernel 6: gather-reduce per node ----------------
__global__ __launch_bounds__(256) void k_gather(const float* __restrict__ ef,
                                                const int* __restrict__ offs,
                                                const int* __restrict__ eidx,
                                                float* __restrict__ out, int N) {
    const int lane = threadIdx.x & 63;
    const int node = blockIdx.x * 4 + (threadIdx.x >> 6);
    if (node >= N) return;

    const int beg = offs[node];
    const int end = offs[node + 1];

    int mi[4], ii[4], jj[4], mode[4];
    #pragma unroll
    for (int t = 0; t < 4; ++t) {
        int c = lane + 64 * t;
        if (c < 16)       { mi[t] = c;                 ii[t] = 0;     jj[t] = 0;     mode[t] = 0; }
        else if (c < 64)  { int u = c - 16; mi[t] = 16 + u / 3; ii[t] = u % 3; jj[t] = 0; mode[t] = 1; }
        else if (c < 208) { int u = c - 64; mi[t] = 32 + u / 9; int rr = u % 9; ii[t] = rr / 3; jj[t] = rr % 3; mode[t] = 2; }
        else              { mi[t] = 0; ii[t] = 0; jj[t] = 0; mode[t] = 3; }
    }

    float acc[4] = {0.f, 0.f, 0.f, 0.f};
    for (int k = beg; k < end; ++k) {
        const int e = eidx[k];
        const float* b = ef + (size_t)e * 52;
        float v = (lane < 51) ? b[lane] : 0.0f;
        float n0 = __shfl(v, 48);
        float n1 = __shfl(v, 49);
        float n2 = __shfl(v, 50);
        #pragma unroll
        for (int t = 0; t < 4; ++t) {
            float mval = __shfl(v, mi[t]);
            float ni = (ii[t] == 0) ? n0 : ((ii[t] == 1) ? n1 : n2);
            float nj = (jj[t] == 0) ? n0 : ((jj[t] == 1) ? n1 : n2);
            float f  = (mode[t] == 0) ? 1.0f
                     : (mode[t] == 1) ? ni
                     : (mode[t] == 2) ? ni * nj
                     : 0.0f;
            acc[t] = fmaf(mval, f, acc[t]);
        }
    }

    const float inv = 1.0f / fmaxf((float)(end - beg), 1.0f);
    float* op = out + (size_t)node * 208;
    op[lane]        = acc[0] * inv;
    op[lane + 64]   = acc[1] * inv;
    op[lane + 128]  = acc[2] * inv;
    if (lane < 16) op[lane + 192] = acc[3] * inv;
}

extern "C" void kernel_launch(void* const* d_in, const int* in_sizes, int n_in,
                              void* d_out, int out_size, void* d_ws, size_t ws_size,
                              hipStream_t stream) {
    const float* pos    = (const float*)d_in[0];
    const int*   A      = (const int*)d_in[1];
    const int*   batch  = (const int*)d_in[2];
    const int*   esrc   = (const int*)d_in[3];
    const int*   edst   = (const int*)d_in[4];
    const float* eshift = (const float*)d_in[5];
    const float* cell   = (const float*)d_in[6];
    const float* embt   = (const float*)d_in[7];
    const float* mw1    = (const float*)d_in[8];
    const float* mb1    = (const float*)d_in[9];
    const float* mw2    = (const float*)d_in[10];
    const float* mb2    = (const float*)d_in[11];
    const float* fw1    = (const float*)d_in[12];
    const float* fb1    = (const float*)d_in[13];
    const float* fw2    = (const float*)d_in[14];
    const float* fb2    = (const float*)d_in[15];
    const float* w3     = (const float*)d_in[16];
    const float* b3     = (const float*)d_in[17];
    float* out = (float*)d_out;

    const int N = in_sizes[1];
    const int E = in_sizes[3];

    char* p = (char*)d_ws;
    auto take = [&](size_t bytes) {
        char* q = p;
        p += (bytes + 255) & ~(size_t)255;
        return q;
    };
    float* w3T    = (float*)take(48 * 64 * 64 * sizeof(float));   // 768 KiB
    float* Ai     = (float*)take((size_t)N * 8 * sizeof(float));
    int*   deg    = (int*)  take((size_t)N * sizeof(int));
    int*   offs   = (int*)  take((size_t)(N + 1) * sizeof(int));
    int*   cursor = (int*)  take((size_t)N * sizeof(int));
    int*   eidx   = (int*)  take((size_t)E * sizeof(int));
    float* ef     = (float*)take((size_t)E * 52 * sizeof(float)); // ~20.8 MiB

    hipMemsetAsync(deg, 0, (size_t)N * sizeof(int), stream);

    k_transpose_w3<<<(48 * 64 * 64 + 255) / 256, 256, 0, stream>>>(w3, w3T);
    k_node_ai<<<(N + 255) / 256, 256, 0, stream>>>(A, embt, mw1, mb1, mw2, mb2, Ai, N);
    k_hist<<<(E + 255) / 256, 256, 0, stream>>>(edst, deg, E);
    k_scan<<<1, 256, 0, stream>>>(deg, offs, cursor, N);
    k_edge<<<(E + 63) / 64, 256, 0, stream>>>(pos, batch, esrc, edst, eshift, cell,
                                              fw1, fb1, fw2, fb2, w3T, b3, Ai,
                                              ef, cursor, eidx, E);
    k_gather<<<(N + 3) / 4, 256, 0, stream>>>(ef, offs, eidx, out, N);
}